// Round 10
// baseline (123.249 us; speedup 1.0000x reference)
//
#include <hip/hip_runtime.h>
#include <hip/hip_fp16.h>
#include <math.h>

using f16    = _Float16;
using f16x8  = __attribute__((ext_vector_type(8))) _Float16;
using f32x16 = __attribute__((ext_vector_type(16))) float;

// ---------------- workspace layout (bytes) ----------------
// x16  : [8][98][98][64] f16 zero ring        =  9,834,496
// ewT  : [72 taps][kg 8][co 128] 16B chunks   =  1,179,648
// fwF  : [kg 16][co2 128] 16B chunks          =     32,768
// ebT  : [8][cq 4][l5 2][rr 16] f32           =      4,096
// comb : [8][py 6][yl 16][kg 16][x 96] 16B    = 18,874,368
#define X16_OFF  0
#define EWT_OFF  9834496
#define FWF_OFF  11014144
#define EBT_OFF  11046912
#define COMB_OFF 11051008

// K1 LDS: xs 23040 | ebT 4096 | per-wave W ring3 (2 waves x 3 x 8192) = 76288
#define EBL     23040
#define WB      27136
#define K1_LDS  76288

__device__ __forceinline__ void gl_lds16(const void* g, void* lds_uniform_base) {
  __builtin_amdgcn_global_load_lds(
      (const __attribute__((address_space(1))) unsigned int*)g,
      (__attribute__((address_space(3))) unsigned int*)lds_uniform_base, 16, 0, 0);
}

// ============ K0: border ring + convert/transpose everything ============
__global__ __launch_bounds__(256) void pce_prep(
    const float* __restrict__ x, const float* __restrict__ ew,
    const float* __restrict__ eb, const float* __restrict__ fw,
    const float* __restrict__ fb, float* __restrict__ out,
    char* __restrict__ ws)
{
  int idx = blockIdx.x * 256 + threadIdx.x;
  if (idx < 397312) {                      // output border ring = bias
    int seg = idx % 388;
    int bc  = idx / 388;
    int co  = bc & 127, bb = bc >> 7;
    int hh, wc;
    if      (seg < 98)  { hh = 0;             wc = seg; }
    else if (seg < 196) { hh = 97;            wc = seg - 98; }
    else if (seg < 292) { hh = seg - 196 + 1; wc = 0; }
    else                { hh = seg - 292 + 1; wc = 97; }
    out[((size_t)(bb * 128 + co) * 98 + hh) * 98 + wc] = fb[co];
  } else if (idx < 397312 + 76832) {       // x16 (b,y,xc), zero ring
    int i = idx - 397312;
    int xc = i % 98;
    int t  = i / 98;
    int y  = t % 98, bb = t / 98;
    char* dst = ws + X16_OFF + (size_t)i * 128;
    if (y >= 1 && y <= 96 && xc >= 1 && xc <= 96) {
      const float* s = x + ((size_t)(bb * 64) * 96 + (y - 1)) * 96 + (xc - 1);
#pragma unroll
      for (int j = 0; j < 8; ++j) {
        f16x8 v;
#pragma unroll
        for (int k = 0; k < 8; ++k) v[k] = (f16)s[(size_t)(j * 8 + k) * 9216];
        *(f16x8*)(dst + j * 16) = v;
      }
    } else {
      f16x8 z;
#pragma unroll
      for (int k = 0; k < 8; ++k) z[k] = (f16)0.f;
#pragma unroll
      for (int j = 0; j < 8; ++j) *(f16x8*)(dst + j * 16) = z;
    }
  } else if (idx < 474144 + 73728) {       // ewT [t][kg][co]
    int i = idx - 474144;
    int co = i & 127, q = (i >> 7) & 7, t = i >> 10;
    int e = t / 9, tap = t - e * 9;
    const float* s = ew + ((size_t)((e * 128 + co) * 64 + q * 8)) * 9 + tap;
    f16x8 v;
#pragma unroll
    for (int j = 0; j < 8; ++j) v[j] = (f16)s[j * 9];
    *(f16x8*)(ws + EWT_OFF + (size_t)i * 16) = v;
  } else if (idx < 547872 + 2048) {        // fwF [kg][co2]
    int j = idx - 547872;
    int co2 = j & 127, kg = j >> 7;
    const float* s = fw + co2 * 128 + kg * 8;
    f16x8 v;
#pragma unroll
    for (int k = 0; k < 8; ++k) v[k] = (f16)s[k];
    *(f16x8*)(ws + FWF_OFF + (size_t)j * 16) = v;
  } else if (idx < 549920 + 1024) {        // ebT[e][cq][l5][rr]
    int k = idx - 549920;
    int rr = k & 15, l5 = (k >> 4) & 1, cq = (k >> 5) & 3, e = k >> 7;
    ((float*)(ws + EBT_OFF))[k] =
        eb[e * 128 + cq * 32 + (rr & 3) + 8 * (rr >> 2) + 4 * l5];
  }
}

// ============ K1: gated expert 3x3 convs -> comb (ws) ============
// block = (b, patch, half), 2 waves. Each wave: 64co x 128px (m2 x n4), with a
// WAVE-PRIVATE W ring-3 in LDS (8KB slots) filled by global_load_lds, lead-2
// prefetch, per-wave counted vmcnt(16). NO barriers after the prologue: xs is
// read-only, W slices are wave-private, comb is register-private.
__global__ __launch_bounds__(128) void pce_expert(
    const float* __restrict__ rw, const float* __restrict__ rb,
    const float* __restrict__ thrp, char* __restrict__ ws)
{
  extern __shared__ char sm[];
  const int tid = threadIdx.x;
  const int blk = (blockIdx.x & 7) * 72 + (blockIdx.x >> 3);  // XCD: b == XCD id
  const int b = blk / 72;
  const int r72 = blk - b * 72;
  const int patch = r72 >> 1, half = r72 & 1;
  const int py = patch / 6, px = patch - py * 6;
  const int lane = tid & 63, wv = tid >> 6;   // wv in {0,1}
  const int l31 = lane & 31, l5 = lane >> 5;
  const int tx = l31 & 15;

  // ---- gates in registers ----
  unsigned mask;
  float garr[8];
  {
    float sy[8], cy[8], sx[8], cx[8];
    float pyc = ((float)py + 0.5f) * (1.f / 6.f);
    float pxc = ((float)px + 0.5f) * (1.f / 6.f);
#pragma unroll
    for (int k = 0; k < 8; ++k) {
      float fr = (float)(1 << k) * 3.14159265358979323846f;
      sy[k] = sinf(pyc * fr); cy[k] = cosf(pyc * fr);
      sx[k] = sinf(pxc * fr); cx[k] = cosf(pxc * fr);
    }
    float thr = thrp[0];
    unsigned m = 0;
#pragma unroll
    for (int e = 0; e < 8; ++e) {
      float l = rb[e];
#pragma unroll
      for (int k = 0; k < 8; ++k) {
        l = fmaf(sy[k], rw[e * 32 + k],      l);
        l = fmaf(cy[k], rw[e * 32 + 8 + k],  l);
        l = fmaf(sx[k], rw[e * 32 + 16 + k], l);
        l = fmaf(cx[k], rw[e * 32 + 24 + k], l);
      }
      float g = 1.f / (1.f + expf(-l));
      g = (g > thr) ? g : 0.f;
      garr[e] = g;
      m |= (g != 0.f ? 1u : 0u) << e;
    }
    mask = (unsigned)__builtin_amdgcn_readfirstlane((int)m);
  }
  auto pick_g = [&](int ee) {
    float v = garr[0];
#pragma unroll
    for (int k = 1; k < 8; ++k) v = (ee == k) ? garr[k] : v;
    return v;
  };

  // ---- prologue DMAs: xs halo (1440 chunks), ebT (256 chunks) ----
  {
    const char* x16 = ws + X16_OFF;
    const int ybase = py * 16 + half * 8;
    const int xbase = px * 16;
#pragma unroll
    for (int itr = 0; itr < 12; ++itr) {
      int ch = tid + itr * 128;
      if (ch < 1440) {
        int j = ch & 7, p = ch >> 3;
        int r = p / 18, c = p - r * 18;
        const char* src = x16 + ((size_t)((b * 98 + ybase + r) * 98 + xbase + c)) * 128
                        + ((j ^ (c & 7)) << 4);
        gl_lds16(src, sm + (itr * 128 + wv * 64) * 16);
      }
    }
  }
#pragma unroll
  for (int itr = 0; itr < 2; ++itr)
    gl_lds16(ws + EBT_OFF + (itr * 128 + tid) * 16,
             sm + EBL + (itr * 128 + wv * 64) * 16);

  const int m0 = wv * 64;                    // this wave's co half
  const char* ewt = ws + EWT_OFF;
  char* const wbase = sm + WB + wv * 24576;  // wave-private ring (3 x 8KB)

  // per-wave W slice DMA: 8 instr x 64 lanes x 16B = 8KB (co in [m0, m0+64))
  auto ISSUE = [&](int slot, int t) {
    const char* wsrc = ewt + (size_t)t * 16384;
    char* wdst = wbase + slot * 8192;
#pragma unroll
    for (int it = 0; it < 8; ++it)
      gl_lds16(wsrc + (it * 128 + m0 + lane) * 16, wdst + it * 1024);
  };

  const int e0 = mask ? (int)__builtin_ctz(mask) : 0;
  ISSUE(0, e0 * 9);
  ISSUE(1, e0 * 9 + 1);
  asm volatile("s_waitcnt vmcnt(16)" ::: "memory");  // xs+ebT landed; primes fly
  __builtin_amdgcn_s_barrier();                      // xs visible to both waves

  int tyb[4];
#pragma unroll
  for (int ni = 0; ni < 4; ++ni) tyb[ni] = ni * 2 + (l31 >> 4);

  f32x16 acc[2][4];
#pragma unroll
  for (int mi = 0; mi < 2; ++mi)
#pragma unroll
    for (int ni = 0; ni < 4; ++ni)
#pragma unroll
      for (int rr = 0; rr < 16; ++rr) acc[mi][ni][rr] = 0.f;
  __half2 comb[2][4][8];
#pragma unroll
  for (int mi = 0; mi < 2; ++mi)
#pragma unroll
    for (int ni = 0; ni < 4; ++ni)
#pragma unroll
      for (int h = 0; h < 8; ++h) comb[mi][ni][h] = __floats2half2_rn(0.f, 0.f);

  int cur = 0;
  auto STEP = [&](int ky, int kx, int pt) {
    const int psl = (cur >= 1) ? cur - 1 : 2;        // (cur+2)%3
    ISSUE(psl, pt);
    asm volatile("s_waitcnt vmcnt(16)" ::: "memory"); // tap issued 2 ago landed
    const char* wcur = wbase + cur * 8192;
    const int cc = tx + kx, sw = cc & 7;
#pragma unroll
    for (int ks = 0; ks < 4; ++ks) {
      const int kg = (ks << 1) | l5;
      f16x8 a0 = *(const f16x8*)(wcur + ((kg << 6) + l31) * 16);
      f16x8 a1 = *(const f16x8*)(wcur + ((kg << 6) + 32 + l31) * 16);
#pragma unroll
      for (int ni = 0; ni < 4; ++ni) {
        const int rr = ((tyb[ni] + ky) * 18 + cc) << 3;
        f16x8 bv = *(const f16x8*)(sm + ((rr + (kg ^ sw)) << 4));
        acc[0][ni] = __builtin_amdgcn_mfma_f32_32x32x16_f16(a0, bv, acc[0][ni], 0, 0, 0);
        acc[1][ni] = __builtin_amdgcn_mfma_f32_32x32x16_f16(a1, bv, acc[1][ni], 0, 0, 0);
      }
    }
    cur = (cur == 2) ? 0 : cur + 1;
  };

  int e = mask ? e0 : -1;
#pragma unroll 1
  while (e >= 0) {
    int nm  = (e < 7) ? (mask >> (e + 1)) : 0;
    int nxt = nm ? e + 1 + (int)__builtin_ctz((unsigned)nm) : -1;
    float g = pick_g(e);
    const int t  = e * 9;
    const int tn = (nxt >= 0) ? nxt * 9 : e0 * 9;   // dummies keep vmcnt uniform

    STEP(0, 0, t + 2);
    STEP(0, 1, t + 3);
    STEP(0, 2, t + 4);
    STEP(1, 0, t + 5);
    STEP(1, 1, t + 6);
    STEP(1, 2, t + 7);
    STEP(2, 0, t + 8);
    STEP(2, 1, tn);          // next expert tap0 (or dummy)
    STEP(2, 2, tn + 1);      // next expert tap1 (or dummy)

    // epilogue: bias (LDS ebT) + relu + gate-accumulate, zero acc
    __half2 g2 = __floats2half2_rn(g, g);
#pragma unroll
    for (int mi = 0; mi < 2; ++mi) {
      const int cq = wv * 2 + mi;
      const float4* ep = (const float4*)(sm + EBL + ((e * 4 + cq) * 2 + l5) * 64);
      float ebv[16];
#pragma unroll
      for (int q = 0; q < 4; ++q) {
        float4 t4 = ep[q];
        ebv[4 * q + 0] = t4.x; ebv[4 * q + 1] = t4.y;
        ebv[4 * q + 2] = t4.z; ebv[4 * q + 3] = t4.w;
      }
#pragma unroll
      for (int ni = 0; ni < 4; ++ni)
#pragma unroll
        for (int h = 0; h < 8; ++h) {
          float v0 = fmaxf(acc[mi][ni][2 * h]     + ebv[2 * h],     0.f);
          float v1 = fmaxf(acc[mi][ni][2 * h + 1] + ebv[2 * h + 1], 0.f);
          comb[mi][ni][h] = __hfma2(g2, __floats2half2_rn(v0, v1), comb[mi][ni][h]);
          acc[mi][ni][2 * h]     = 0.f;
          acc[mi][ni][2 * h + 1] = 0.f;
        }
    }
    e = nxt;
  }

  // ---- store comb -> ws comb[b][py][yl][kg][x] 16B chunks (coalesced) ----
  {
    char* cb = ws + COMB_OFF + (size_t)((b * 6 + py) * 16) * 24576;
#pragma unroll
    for (int mi = 0; mi < 2; ++mi) {
      const int kgb = (m0 + mi * 32) >> 3;
#pragma unroll
      for (int ni = 0; ni < 4; ++ni) {
        int pxl = ni * 32 + l31;
        int yl = half * 8 + (pxl >> 4);
        int xg = px * 16 + (pxl & 15);
#pragma unroll
        for (int q = 0; q < 4; ++q) {
          uint2 u;
          u.x = *(unsigned*)&comb[mi][ni][2 * q];
          u.y = *(unsigned*)&comb[mi][ni][2 * q + 1];
          *(uint2*)(cb + ((size_t)(yl * 16 + kgb + q) * 96 + xg) * 16 + l5 * 8) = u;
        }
      }
    }
  }
  asm volatile("s_waitcnt vmcnt(0)" ::: "memory");  // drain dead DMAs
}

// ============ K2: 1x1 conv row-owner GEMM + bias ============
// block = (b, py, yhalf, co2-quarter). Full 96-wide rows -> contiguous stores.
__global__ __launch_bounds__(256, 4) void pce_final(
    const char* __restrict__ ws, const float* __restrict__ fb, float* __restrict__ out)
{
  const int tid = threadIdx.x;
  const int blk = (blockIdx.x & 7) * 48 + (blockIdx.x >> 3);  // XCD: b == XCD id
  const int b = blk / 48;
  const int r48 = blk - b * 48;
  const int py = r48 >> 3, yh = (r48 >> 2) & 1, cq = r48 & 3;
  const int lane = tid & 63, wv = tid >> 6;
  const int l31 = lane & 31, l5 = lane >> 5;

  f16x8 a[8];
#pragma unroll
  for (int ks = 0; ks < 8; ++ks)
    a[ks] = *(const f16x8*)(ws + FWF_OFF + (((ks * 2 + l5) * 128) + cq * 32 + l31) * 16);

  float fbv[16];
#pragma unroll
  for (int rr = 0; rr < 16; ++rr)
    fbv[rr] = fb[cq * 32 + (rr & 3) + 8 * (rr >> 2) + 4 * l5];

  const char* cb = ws + COMB_OFF + (size_t)((b * 6 + py) * 16) * 24576;

#pragma unroll 1
  for (int yi = 0; yi < 2; ++yi) {
    const int yl = yh * 8 + yi * 4 + wv;
    f32x16 acc[3];
#pragma unroll
    for (int n = 0; n < 3; ++n)
#pragma unroll
      for (int rr = 0; rr < 16; ++rr) acc[n][rr] = 0.f;

#pragma unroll
    for (int ks = 0; ks < 8; ++ks) {
      const char* rowp = cb + (size_t)(yl * 16 + ks * 2 + l5) * 1536;
#pragma unroll
      for (int n = 0; n < 3; ++n) {
        f16x8 bv = *(const f16x8*)(rowp + (n * 32 + l31) * 16);
        acc[n] = __builtin_amdgcn_mfma_f32_32x32x16_f16(a[ks], bv, acc[n], 0, 0, 0);
      }
    }

    const int y = py * 16 + yl + 1;
#pragma unroll
    for (int rr = 0; rr < 16; ++rr) {
      int co2 = cq * 32 + (rr & 3) + 8 * (rr >> 2) + 4 * l5;
      float* op = out + ((size_t)(b * 128 + co2) * 98 + y) * 98 + 1 + l31;
      float bias = fbv[rr];
#pragma unroll
      for (int n = 0; n < 3; ++n) op[n * 32] = acc[n][rr] + bias;
    }
  }
}

extern "C" void kernel_launch(void* const* d_in, const int* in_sizes, int n_in,
                              void* d_out, int out_size, void* d_ws, size_t ws_size,
                              hipStream_t stream) {
  const float* x   = (const float*)d_in[0];
  const float* ew  = (const float*)d_in[1];
  const float* ebp = (const float*)d_in[2];
  const float* rw  = (const float*)d_in[3];
  const float* rb  = (const float*)d_in[4];
  const float* fw  = (const float*)d_in[5];
  const float* fb  = (const float*)d_in[6];
  const float* thr = (const float*)d_in[7];
  float* out = (float*)d_out;
  char* ws = (char*)d_ws;

  hipFuncSetAttribute((const void*)pce_expert,
                      hipFuncAttributeMaxDynamicSharedMemorySize, K1_LDS);

  hipLaunchKernelGGL(pce_prep,   dim3(2153), dim3(256), 0, stream,
                     x, ew, ebp, fw, fb, out, ws);
  hipLaunchKernelGGL(pce_expert, dim3(576),  dim3(128), K1_LDS, stream,
                     rw, rb, thr, ws);
  hipLaunchKernelGGL(pce_final,  dim3(384),  dim3(256), 0, stream, ws, fb, out);
}

// Round 11
// 98.692 us; speedup vs baseline: 1.2488x; 1.2488x over previous
//
#include <hip/hip_runtime.h>
#include <hip/hip_fp16.h>
#include <math.h>

using f16    = _Float16;
using f16x8  = __attribute__((ext_vector_type(8))) _Float16;
using f32x16 = __attribute__((ext_vector_type(16))) float;

// ---------------- workspace layout (bytes) ----------------
// x16  : [8][98][98][64] f16 zero ring        =  9,834,496
// ewT  : [72 taps][kg 8][co 128] 16B chunks   =  1,179,648
// fwF  : [kg 16][co2 128] 16B chunks          =     32,768
// ebT  : [8][cq 4][l5 2][rr 16] f32           =      4,096
// comb : [8][py 6][yl 16][kg 16][x 96] 16B    = 18,874,368
#define X16_OFF  0
#define EWT_OFF  9834496
#define FWF_OFF  11014144
#define EBT_OFF  11046912
#define COMB_OFF 11051008

// K1 LDS: xs 23040 | ebT 4096 | W half-tap ring3 (3 x 8192) = 51712 total
// -> 3 blocks/CU (12 waves/CU)
#define EBL     23040
#define WSL     27136
#define K1_LDS  51712

__device__ __forceinline__ void gl_lds16(const void* g, void* lds_uniform_base) {
  __builtin_amdgcn_global_load_lds(
      (const __attribute__((address_space(1))) unsigned int*)g,
      (__attribute__((address_space(3))) unsigned int*)lds_uniform_base, 16, 0, 0);
}

// ============ K0: border ring + convert/transpose everything ============
__global__ __launch_bounds__(256) void pce_prep(
    const float* __restrict__ x, const float* __restrict__ ew,
    const float* __restrict__ eb, const float* __restrict__ fw,
    const float* __restrict__ fb, float* __restrict__ out,
    char* __restrict__ ws)
{
  int idx = blockIdx.x * 256 + threadIdx.x;
  if (idx < 397312) {                      // output border ring = bias
    int seg = idx % 388;
    int bc  = idx / 388;
    int co  = bc & 127, bb = bc >> 7;
    int hh, wc;
    if      (seg < 98)  { hh = 0;             wc = seg; }
    else if (seg < 196) { hh = 97;            wc = seg - 98; }
    else if (seg < 292) { hh = seg - 196 + 1; wc = 0; }
    else                { hh = seg - 292 + 1; wc = 97; }
    out[((size_t)(bb * 128 + co) * 98 + hh) * 98 + wc] = fb[co];
  } else if (idx < 397312 + 76832) {       // x16 (b,y,xc), zero ring
    int i = idx - 397312;
    int xc = i % 98;
    int t  = i / 98;
    int y  = t % 98, bb = t / 98;
    char* dst = ws + X16_OFF + (size_t)i * 128;
    if (y >= 1 && y <= 96 && xc >= 1 && xc <= 96) {
      const float* s = x + ((size_t)(bb * 64) * 96 + (y - 1)) * 96 + (xc - 1);
#pragma unroll
      for (int j = 0; j < 8; ++j) {
        f16x8 v;
#pragma unroll
        for (int k = 0; k < 8; ++k) v[k] = (f16)s[(size_t)(j * 8 + k) * 9216];
        *(f16x8*)(dst + j * 16) = v;
      }
    } else {
      f16x8 z;
#pragma unroll
      for (int k = 0; k < 8; ++k) z[k] = (f16)0.f;
#pragma unroll
      for (int j = 0; j < 8; ++j) *(f16x8*)(dst + j * 16) = z;
    }
  } else if (idx < 474144 + 73728) {       // ewT [t][kg][co]
    int i = idx - 474144;
    int co = i & 127, q = (i >> 7) & 7, t = i >> 10;
    int e = t / 9, tap = t - e * 9;
    const float* s = ew + ((size_t)((e * 128 + co) * 64 + q * 8)) * 9 + tap;
    f16x8 v;
#pragma unroll
    for (int j = 0; j < 8; ++j) v[j] = (f16)s[j * 9];
    *(f16x8*)(ws + EWT_OFF + (size_t)i * 16) = v;
  } else if (idx < 547872 + 2048) {        // fwF [kg][co2]
    int j = idx - 547872;
    int co2 = j & 127, kg = j >> 7;
    const float* s = fw + co2 * 128 + kg * 8;
    f16x8 v;
#pragma unroll
    for (int k = 0; k < 8; ++k) v[k] = (f16)s[k];
    *(f16x8*)(ws + FWF_OFF + (size_t)j * 16) = v;
  } else if (idx < 549920 + 1024) {        // ebT[e][cq][l5][rr]
    int k = idx - 549920;
    int rr = k & 15, l5 = (k >> 4) & 1, cq = (k >> 5) & 3, e = k >> 7;
    ((float*)(ws + EBT_OFF))[k] =
        eb[e * 128 + cq * 32 + (rr & 3) + 8 * (rr >> 2) + 4 * l5];
  }
}

// ============ K1: gated expert 3x3 convs -> comb (ws) ============
// block = (b, patch, half), 4 waves, R8 sync structure at HALF-TAP cadence:
// W half-tap (4 kg x 128 co = 8KB) ring-3 shared slots, counted vmcnt(4),
// 2 barriers per half-step. 51.7KB LDS -> 3 blocks/CU = 12 waves/CU.
__global__ __launch_bounds__(256, 3) void pce_expert(
    const float* __restrict__ rw, const float* __restrict__ rb,
    const float* __restrict__ thrp, char* __restrict__ ws)
{
  extern __shared__ char sm[];
  const int tid = threadIdx.x;
  const int blk = (blockIdx.x & 7) * 72 + (blockIdx.x >> 3);  // XCD: b == XCD id
  const int b = blk / 72;
  const int r72 = blk - b * 72;
  const int patch = r72 >> 1, half = r72 & 1;
  const int py = patch / 6, px = patch - py * 6;
  const int lane = tid & 63, wv = tid >> 6;
  const int l31 = lane & 31, l5 = lane >> 5;
  const int tx = l31 & 15;

  // ---- gates in registers ----
  unsigned mask;
  float garr[8];
  {
    float sy[8], cy[8], sx[8], cx[8];
    float pyc = ((float)py + 0.5f) * (1.f / 6.f);
    float pxc = ((float)px + 0.5f) * (1.f / 6.f);
#pragma unroll
    for (int k = 0; k < 8; ++k) {
      float fr = (float)(1 << k) * 3.14159265358979323846f;
      sy[k] = sinf(pyc * fr); cy[k] = cosf(pyc * fr);
      sx[k] = sinf(pxc * fr); cx[k] = cosf(pxc * fr);
    }
    float thr = thrp[0];
    unsigned m = 0;
#pragma unroll
    for (int e = 0; e < 8; ++e) {
      float l = rb[e];
#pragma unroll
      for (int k = 0; k < 8; ++k) {
        l = fmaf(sy[k], rw[e * 32 + k],      l);
        l = fmaf(cy[k], rw[e * 32 + 8 + k],  l);
        l = fmaf(sx[k], rw[e * 32 + 16 + k], l);
        l = fmaf(cx[k], rw[e * 32 + 24 + k], l);
      }
      float g = 1.f / (1.f + expf(-l));
      g = (g > thr) ? g : 0.f;
      garr[e] = g;
      m |= (g != 0.f ? 1u : 0u) << e;
    }
    mask = (unsigned)__builtin_amdgcn_readfirstlane((int)m);
  }
  auto pick_g = [&](int ee) {
    float v = garr[0];
#pragma unroll
    for (int k = 1; k < 8; ++k) v = (ee == k) ? garr[k] : v;
    return v;
  };

  // ---- prologue DMAs: xs halo (1440 chunks), ebT (256 chunks) ----
  {
    const char* x16 = ws + X16_OFF;
    const int ybase = py * 16 + half * 8;
    const int xbase = px * 16;
#pragma unroll
    for (int itr = 0; itr < 6; ++itr) {
      int ch = tid + itr * 256;
      if (ch < 1440) {
        int j = ch & 7, p = ch >> 3;
        int r = p / 18, c = p - r * 18;
        const char* src = x16 + ((size_t)((b * 98 + ybase + r) * 98 + xbase + c)) * 128
                        + ((j ^ (c & 7)) << 4);
        gl_lds16(src, sm + (itr * 256 + wv * 64) * 16);
      }
    }
  }
  gl_lds16(ws + EBT_OFF + tid * 16, sm + EBL + wv * 1024);

  const char* ewt = ws + EWT_OFF;
  // half-tap slot DMA: 8KB = 2 instr/thread (thread-linear dest)
  auto ISSUE = [&](int slot, size_t byteofs) {
    const char* wsrc = ewt + byteofs;
    char* wdst = sm + WSL + slot * 8192;
#pragma unroll
    for (int it = 0; it < 2; ++it)
      gl_lds16(wsrc + (it * 256 + tid) * 16, wdst + (it * 256 + wv * 64) * 16);
  };

  const int e0 = mask ? (int)__builtin_ctz(mask) : 0;
  ISSUE(0, (size_t)(e0 * 9) * 16384);          // tap0 h0
  ISSUE(1, (size_t)(e0 * 9) * 16384 + 8192);   // tap0 h1
  asm volatile("s_waitcnt vmcnt(4)" ::: "memory");  // xs+ebT landed; primes fly
  __builtin_amdgcn_s_barrier();

  const int m0 = (wv & 1) * 64;              // co half
  const int n0 = (wv >> 1) * 64;             // px quarter
  const int tyb0 = (n0 >> 4) + (l31 >> 4);

  f32x16 acc[2][2];
#pragma unroll
  for (int mi = 0; mi < 2; ++mi)
#pragma unroll
    for (int ni = 0; ni < 2; ++ni)
#pragma unroll
      for (int rr = 0; rr < 16; ++rr) acc[mi][ni][rr] = 0.f;
  __half2 comb[2][2][8];
#pragma unroll
  for (int mi = 0; mi < 2; ++mi)
#pragma unroll
    for (int ni = 0; ni < 2; ++ni)
#pragma unroll
      for (int h = 0; h < 8; ++h) comb[mi][ni][h] = __floats2half2_rn(0.f, 0.f);

  int cur = 0;
  // one half-step: WAR barrier; issue half-tap (lead 2); counted wait; ready
  // barrier; 8 ds_reads + 8 MFMAs on slot `cur`.
  auto STEPH = [&](int ky, int kx, int h, size_t pofs) {
    __builtin_amdgcn_s_barrier();            // WAR: slot (cur+2)%3 free
    const int psl = (cur >= 1) ? cur - 1 : 2;   // (cur+2)%3
    ISSUE(psl, pofs);
    asm volatile("s_waitcnt vmcnt(4)" ::: "memory");  // slot cur (2 steps old) in
    __builtin_amdgcn_s_barrier();            // all waves' slices of cur landed
    const char* wcur = sm + WSL + cur * 8192;
    const int cc = tx + kx, sw = cc & 7;
    const int r0 = ((tyb0 + ky) * 18 + cc) << 3;
    const int r1 = ((tyb0 + 2 + ky) * 18 + cc) << 3;
#pragma unroll
    for (int ks = 0; ks < 2; ++ks) {
      const int kgl = (ks << 1) | l5;        // in-slot kg 0..3
      const int kg  = (h << 2) | kgl;        // full kg 0..7 (xs swizzle)
      f16x8 a0 = *(const f16x8*)(wcur + ((kgl << 7) + m0 + l31) * 16);
      f16x8 a1 = *(const f16x8*)(wcur + ((kgl << 7) + m0 + 32 + l31) * 16);
      f16x8 b0 = *(const f16x8*)(sm + ((r0 + (kg ^ sw)) << 4));
      f16x8 b1 = *(const f16x8*)(sm + ((r1 + (kg ^ sw)) << 4));
      acc[0][0] = __builtin_amdgcn_mfma_f32_32x32x16_f16(a0, b0, acc[0][0], 0, 0, 0);
      acc[0][1] = __builtin_amdgcn_mfma_f32_32x32x16_f16(a0, b1, acc[0][1], 0, 0, 0);
      acc[1][0] = __builtin_amdgcn_mfma_f32_32x32x16_f16(a1, b0, acc[1][0], 0, 0, 0);
      acc[1][1] = __builtin_amdgcn_mfma_f32_32x32x16_f16(a1, b1, acc[1][1], 0, 0, 0);
    }
    cur = (cur == 2) ? 0 : cur + 1;
  };

  int e = mask ? e0 : -1;
#pragma unroll 1
  while (e >= 0) {
    int nm  = (e < 7) ? (mask >> (e + 1)) : 0;
    int nxt = nm ? e + 1 + (int)__builtin_ctz((unsigned)nm) : -1;
    float g = pick_g(e);
    const size_t t  = (size_t)(e * 9) * 16384;
    const size_t tn = (size_t)(((nxt >= 0) ? nxt : e0) * 9) * 16384; // dummy ok

    STEPH(0, 0, 0, t + 1 * 16384);
    STEPH(0, 0, 1, t + 1 * 16384 + 8192);
    STEPH(0, 1, 0, t + 2 * 16384);
    STEPH(0, 1, 1, t + 2 * 16384 + 8192);
    STEPH(0, 2, 0, t + 3 * 16384);
    STEPH(0, 2, 1, t + 3 * 16384 + 8192);
    STEPH(1, 0, 0, t + 4 * 16384);
    STEPH(1, 0, 1, t + 4 * 16384 + 8192);
    STEPH(1, 1, 0, t + 5 * 16384);
    STEPH(1, 1, 1, t + 5 * 16384 + 8192);
    STEPH(1, 2, 0, t + 6 * 16384);
    STEPH(1, 2, 1, t + 6 * 16384 + 8192);
    STEPH(2, 0, 0, t + 7 * 16384);
    STEPH(2, 0, 1, t + 7 * 16384 + 8192);
    STEPH(2, 1, 0, t + 8 * 16384);
    STEPH(2, 1, 1, t + 8 * 16384 + 8192);
    STEPH(2, 2, 0, tn);                      // next expert tap0 h0 (or dummy)
    STEPH(2, 2, 1, tn + 8192);               // next expert tap0 h1 (or dummy)

    // epilogue: bias (LDS ebT) + relu + gate-accumulate, zero acc
    __half2 g2 = __floats2half2_rn(g, g);
#pragma unroll
    for (int mi = 0; mi < 2; ++mi) {
      const int cq = (wv & 1) * 2 + mi;
      const float4* ep = (const float4*)(sm + EBL + ((e * 4 + cq) * 2 + l5) * 64);
      float ebv[16];
#pragma unroll
      for (int q = 0; q < 4; ++q) {
        float4 t4 = ep[q];
        ebv[4 * q + 0] = t4.x; ebv[4 * q + 1] = t4.y;
        ebv[4 * q + 2] = t4.z; ebv[4 * q + 3] = t4.w;
      }
#pragma unroll
      for (int ni = 0; ni < 2; ++ni)
#pragma unroll
        for (int h = 0; h < 8; ++h) {
          float v0 = fmaxf(acc[mi][ni][2 * h]     + ebv[2 * h],     0.f);
          float v1 = fmaxf(acc[mi][ni][2 * h + 1] + ebv[2 * h + 1], 0.f);
          comb[mi][ni][h] = __hfma2(g2, __floats2half2_rn(v0, v1), comb[mi][ni][h]);
          acc[mi][ni][2 * h]     = 0.f;
          acc[mi][ni][2 * h + 1] = 0.f;
        }
    }
    e = nxt;
  }

  // ---- store comb -> ws comb[b][py][yl][kg][x] 16B chunks (coalesced) ----
  {
    char* cb = ws + COMB_OFF + (size_t)((b * 6 + py) * 16) * 24576;
#pragma unroll
    for (int mi = 0; mi < 2; ++mi) {
      const int kgb = (m0 + mi * 32) >> 3;
#pragma unroll
      for (int ni = 0; ni < 2; ++ni) {
        int pxl = n0 + ni * 32 + l31;
        int yl = half * 8 + (pxl >> 4);
        int xg = px * 16 + (pxl & 15);
#pragma unroll
        for (int q = 0; q < 4; ++q) {
          uint2 u;
          u.x = *(unsigned*)&comb[mi][ni][2 * q];
          u.y = *(unsigned*)&comb[mi][ni][2 * q + 1];
          *(uint2*)(cb + ((size_t)(yl * 16 + kgb + q) * 96 + xg) * 16 + l5 * 8) = u;
        }
      }
    }
  }
  asm volatile("s_waitcnt vmcnt(0)" ::: "memory");  // drain dead DMAs
}

// ============ K2: 1x1 conv row-owner GEMM + bias ============
// block = (b, py, yhalf, co2-quarter). Full 96-wide rows -> contiguous stores.
__global__ __launch_bounds__(256, 4) void pce_final(
    const char* __restrict__ ws, const float* __restrict__ fb, float* __restrict__ out)
{
  const int tid = threadIdx.x;
  const int blk = (blockIdx.x & 7) * 48 + (blockIdx.x >> 3);  // XCD: b == XCD id
  const int b = blk / 48;
  const int r48 = blk - b * 48;
  const int py = r48 >> 3, yh = (r48 >> 2) & 1, cq = r48 & 3;
  const int lane = tid & 63, wv = tid >> 6;
  const int l31 = lane & 31, l5 = lane >> 5;

  f16x8 a[8];
#pragma unroll
  for (int ks = 0; ks < 8; ++ks)
    a[ks] = *(const f16x8*)(ws + FWF_OFF + (((ks * 2 + l5) * 128) + cq * 32 + l31) * 16);

  float fbv[16];
#pragma unroll
  for (int rr = 0; rr < 16; ++rr)
    fbv[rr] = fb[cq * 32 + (rr & 3) + 8 * (rr >> 2) + 4 * l5];

  const char* cb = ws + COMB_OFF + (size_t)((b * 6 + py) * 16) * 24576;

#pragma unroll 1
  for (int yi = 0; yi < 2; ++yi) {
    const int yl = yh * 8 + yi * 4 + wv;
    f32x16 acc[3];
#pragma unroll
    for (int n = 0; n < 3; ++n)
#pragma unroll
      for (int rr = 0; rr < 16; ++rr) acc[n][rr] = 0.f;

#pragma unroll
    for (int ks = 0; ks < 8; ++ks) {
      const char* rowp = cb + (size_t)(yl * 16 + ks * 2 + l5) * 1536;
#pragma unroll
      for (int n = 0; n < 3; ++n) {
        f16x8 bv = *(const f16x8*)(rowp + (n * 32 + l31) * 16);
        acc[n] = __builtin_amdgcn_mfma_f32_32x32x16_f16(a[ks], bv, acc[n], 0, 0, 0);
      }
    }

    const int y = py * 16 + yl + 1;
#pragma unroll
    for (int rr = 0; rr < 16; ++rr) {
      int co2 = cq * 32 + (rr & 3) + 8 * (rr >> 2) + 4 * l5;
      float* op = out + ((size_t)(b * 128 + co2) * 98 + y) * 98 + 1 + l31;
      float bias = fbv[rr];
#pragma unroll
      for (int n = 0; n < 3; ++n) op[n * 32] = acc[n][rr] + bias;
    }
  }
}

extern "C" void kernel_launch(void* const* d_in, const int* in_sizes, int n_in,
                              void* d_out, int out_size, void* d_ws, size_t ws_size,
                              hipStream_t stream) {
  const float* x   = (const float*)d_in[0];
  const float* ew  = (const float*)d_in[1];
  const float* ebp = (const float*)d_in[2];
  const float* rw  = (const float*)d_in[3];
  const float* rb  = (const float*)d_in[4];
  const float* fw  = (const float*)d_in[5];
  const float* fb  = (const float*)d_in[6];
  const float* thr = (const float*)d_in[7];
  float* out = (float*)d_out;
  char* ws = (char*)d_ws;

  hipFuncSetAttribute((const void*)pce_expert,
                      hipFuncAttributeMaxDynamicSharedMemorySize, K1_LDS);

  hipLaunchKernelGGL(pce_prep,   dim3(2153), dim3(256), 0, stream,
                     x, ew, ebp, fw, fb, out, ws);
  hipLaunchKernelGGL(pce_expert, dim3(576),  dim3(256), K1_LDS, stream,
                     rw, rb, thr, ws);
  hipLaunchKernelGGL(pce_final,  dim3(384),  dim3(256), 0, stream, ws, fb, out);
}